// Round 1
// baseline (288.750 us; speedup 1.0000x reference)
//
#include <hip/hip_runtime.h>
#include <hip/hip_bf16.h>

#define B_   8
#define Q_   2048
#define C_   256
#define NPER 64
#define H1_  256
#define H2_  64
#define ROWS (B_ * Q_)          // 16384
#define EPSN 1e-5f

typedef __bf16 bf16x8 __attribute__((ext_vector_type(8)));
typedef float  f32x4  __attribute__((ext_vector_type(4)));

// ---------------- K0: pack W1/W2 into MFMA B-fragment order (bf16), zero partials ----
// B-frag layout for mfma_f32_16x16x32_bf16: lane l supplies B[k=(l>>4)*8+j][n=(l&15)].
// W1p flat idx = (((w*4+ct)*8+ks)*64+l)*8+j  covering cols c = w*64+ct*16+(l&15), k = ks*32+(l>>4)*8+j
// W2p flat idx = (((w*8+ks))*64+l)*8+j       covering cols c2 = w*16+(l&15)
__global__ __launch_bounds__(256) void k0_pack(const float* __restrict__ W1,
                                               const float* __restrict__ W2,
                                               __bf16* __restrict__ W1p,
                                               __bf16* __restrict__ W2p,
                                               float* __restrict__ zero_base) {
    int idx = blockIdx.x * 256 + threadIdx.x;   // 0 .. 81919
    if (idx < 65536) {
        int j = idx & 7, l = (idx >> 3) & 63, rest = idx >> 9;
        int ks = rest & 7, ct = (rest >> 3) & 3, w = rest >> 5;
        int k = ks * 32 + ((l >> 4) << 3) + j;
        int c = w * 64 + ct * 16 + (l & 15);
        W1p[idx] = (__bf16)W1[k * H1_ + c];
    } else {
        int i2 = idx - 65536;                   // < 16384
        int j = i2 & 7, l = (i2 >> 3) & 63, rest = i2 >> 9;
        int ks = rest & 7, w = rest >> 3;
        int k = ks * 32 + ((l >> 4) << 3) + j;
        int c2 = w * 16 + (l & 15);
        W2p[i2] = (__bf16)W2[k * H2_ + c2];
    }
    if (idx < 24576) zero_base[idx] = 0.0f;     // p1s,p1q,p2s,p2q contiguous
}

// ---------------- K1a: tokpart = tokens @ W1[:C] (bf16 MFMA), col stats, coarse -----
__global__ __launch_bounds__(256) void k1a(const float* __restrict__ tokens,
                                           const float* __restrict__ Wc,
                                           const float* __restrict__ bc,
                                           const __bf16* __restrict__ W1p,
                                           float* __restrict__ tokpart,
                                           float* __restrict__ coarse_out,
                                           float* __restrict__ p1s,
                                           float* __restrict__ p1q) {
    __shared__ __align__(16) __bf16 Alds[64 * 264];   // 64 rows, stride 264 bf16 (pad 8)
    __shared__ float wcs[C_ * 3 + 3];
    int t = threadIdx.x;
    int rowbase = blockIdx.x * 64;

    for (int i = t; i < C_ * 3 + 3; i += 256)
        wcs[i] = (i < C_ * 3) ? Wc[i] : bc[i - C_ * 3];
    for (int r = 0; r < 64; ++r)
        Alds[r * 264 + t] = (__bf16)tokens[(size_t)(rowbase + r) * C_ + t];
    __syncthreads();

    int w = t >> 6, l = t & 63, quad = l >> 4, col = l & 15;
    int slot = blockIdx.x & 31;

    for (int ct = 0; ct < 4; ++ct) {
        int c = w * 64 + ct * 16 + col;
        bf16x8 bfrag[8];
#pragma unroll
        for (int ks = 0; ks < 8; ++ks)
            bfrag[ks] = *(const bf16x8*)(W1p + ((((w * 4 + ct) * 8 + ks) * 64 + l) * 8));
        float s = 0.f, q = 0.f;
        for (int rt = 0; rt < 4; ++rt) {
            f32x4 acc = {0.f, 0.f, 0.f, 0.f};
#pragma unroll
            for (int ks = 0; ks < 8; ++ks) {
                bf16x8 a = *(const bf16x8*)(&Alds[(rt * 16 + col) * 264 + ks * 32 + quad * 8]);
                acc = __builtin_amdgcn_mfma_f32_16x16x32_bf16(a, bfrag[ks], acc, 0, 0, 0);
            }
            int rbase = rowbase + rt * 16 + quad * 4;
#pragma unroll
            for (int r = 0; r < 4; ++r) {
                float v = acc[r];
                tokpart[(size_t)(rbase + r) * C_ + c] = v;
                s += v; q += v * v;
            }
        }
        s += __shfl_xor(s, 16, 64); s += __shfl_xor(s, 32, 64);
        q += __shfl_xor(q, 16, 64); q += __shfl_xor(q, 32, 64);
        if (l < 16) {
            atomicAdd(p1s + slot * C_ + c, s);
            atomicAdd(p1q + slot * C_ + c, q);
        }
    }
    // coarse = tokens @ Wc + bc (from bf16-staged tokens; threshold allows it)
    if (t < 192) {
        int r = t / 3, j = t - 3 * (t / 3);
        float acc = wcs[C_ * 3 + j];
        for (int k = 0; k < C_; ++k)
            acc += (float)Alds[r * 264 + k] * wcs[k * 3 + j];
        coarse_out[(size_t)(rowbase + r) * 3 + j] = acc;
    }
}

// ---------------- K1b: BN1 params (var decomposition over product set) --------------
__global__ void k1b(const float* __restrict__ grid, const float* __restrict__ W1,
                    const float* __restrict__ gamma1, const float* __restrict__ beta1,
                    const float* __restrict__ p1s, const float* __restrict__ p1q,
                    float* __restrict__ a1o, float* __restrict__ d1o) {
    int t = threadIdx.x;                    // 256 = channel
    float S = 0.f, Qq = 0.f;
    for (int s = 0; s < 32; ++s) { S += p1s[s * C_ + t]; Qq += p1q[s * C_ + t]; }
    float mean_t = S / (float)ROWS;
    float var_t = Qq / (float)ROWS - mean_t * mean_t;
    float wx = W1[C_ * H1_ + t];            // W1[256][t]
    float wy = W1[(C_ + 1) * H1_ + t];      // W1[257][t]
    float mg = 0.f, qg = 0.f;
    for (int n = 0; n < 64; ++n) {
        float gv = grid[2 * n] * wx + grid[2 * n + 1] * wy;
        mg += gv; qg += gv * gv;
    }
    mg *= (1.f / 64.f);
    float var_g = qg * (1.f / 64.f) - mg * mg;
    float a1 = gamma1[t] * rsqrtf(var_t + var_g + EPSN);
    a1o[t] = a1;
    d1o[t] = beta1[t] - a1 * (mean_t + mg); // b1 cancels exactly
}

// ---------------- K2: pass 1 — h2pre = y1@W2 + b2, accumulate BN2 stats -------------
__global__ __launch_bounds__(256) void k2(const float* __restrict__ tokpart,
                                          const float* __restrict__ grid,
                                          const float* __restrict__ W1,
                                          const __bf16* __restrict__ W2p,
                                          const float* __restrict__ a1,
                                          const float* __restrict__ d1,
                                          const float* __restrict__ b2,
                                          float* __restrict__ p2s,
                                          float* __restrict__ p2q) {
    __shared__ __align__(16) __bf16 y1[64 * 264];
    __shared__ float gl[128];
    int t = threadIdx.x;
    int row = blockIdx.x;
    if (t < 128) gl[t] = grid[t];
    float a1v = a1[t], d1v = d1[t];
    float base = a1v * tokpart[(size_t)row * C_ + t] + d1v;
    float wgx = a1v * W1[C_ * H1_ + t];
    float wgy = a1v * W1[(C_ + 1) * H1_ + t];
    __syncthreads();
    for (int n = 0; n < 64; ++n) {
        float v = fmaf(wgy, gl[2 * n + 1], fmaf(wgx, gl[2 * n], base));
        y1[n * 264 + t] = (__bf16)fmaxf(v, 0.f);
    }
    __syncthreads();

    int w = t >> 6, l = t & 63, quad = l >> 4, col = l & 15;
    int c2 = w * 16 + col;                  // waves own disjoint 16-col chunks of H2
    bf16x8 bfrag[8];
#pragma unroll
    for (int ks = 0; ks < 8; ++ks)
        bfrag[ks] = *(const bf16x8*)(W2p + (((w * 8 + ks) * 64 + l) * 8));
    float b2v = b2[c2];
    float s = 0.f, q = 0.f;
    for (int rt = 0; rt < 4; ++rt) {
        f32x4 acc = {0.f, 0.f, 0.f, 0.f};
#pragma unroll
        for (int ks = 0; ks < 8; ++ks) {
            bf16x8 a = *(const bf16x8*)(&y1[(rt * 16 + col) * 264 + ks * 32 + quad * 8]);
            acc = __builtin_amdgcn_mfma_f32_16x16x32_bf16(a, bfrag[ks], acc, 0, 0, 0);
        }
#pragma unroll
        for (int r = 0; r < 4; ++r) {
            float h = acc[r] + b2v;
            s += h; q += h * h;
        }
    }
    s += __shfl_xor(s, 16, 64); s += __shfl_xor(s, 32, 64);
    q += __shfl_xor(q, 16, 64); q += __shfl_xor(q, 32, 64);
    if (l < 16) {
        int slot = row & 63;
        atomicAdd(p2s + slot * H2_ + c2, s);
        atomicAdd(p2q + slot * H2_ + c2, q);
    }
}

// ---------------- K2b: BN2 params ---------------------------------------------------
__global__ void k2b(const float* __restrict__ p2s, const float* __restrict__ p2q,
                    const float* __restrict__ gamma2, const float* __restrict__ beta2,
                    float* __restrict__ a2o, float* __restrict__ d2o) {
    int t = threadIdx.x;                    // 64 = channel
    float S = 0.f, Qq = 0.f;
    for (int s = 0; s < 64; ++s) { S += p2s[s * H2_ + t]; Qq += p2q[s * H2_ + t]; }
    const float invN = 1.f / ((float)ROWS * 64.f);
    float mean = S * invN;
    float var = Qq * invN - mean * mean;
    float a2 = gamma2[t] * rsqrtf(var + EPSN);
    a2o[t] = a2;
    d2o[t] = beta2[t] - a2 * mean;
}

// ---------------- K3: pass 2 — recompute, BN2+ReLU, @W3, + coarse, store fine -------
__global__ __launch_bounds__(256) void k3(const float* __restrict__ tokpart,
                                          const float* __restrict__ grid,
                                          const float* __restrict__ W1,
                                          const __bf16* __restrict__ W2p,
                                          const float* __restrict__ a1,
                                          const float* __restrict__ d1,
                                          const float* __restrict__ b2,
                                          const float* __restrict__ a2,
                                          const float* __restrict__ d2,
                                          const float* __restrict__ W3,
                                          const float* __restrict__ b3,
                                          const float* __restrict__ coarse,
                                          float* __restrict__ fine) {
    __shared__ __align__(16) __bf16 y1[64 * 264];
    __shared__ float y2[64 * 65];           // stride 65: conflict-free column dots
    __shared__ float gl[128];
    __shared__ float w3s[H2_ * 3 + 3];
    int t = threadIdx.x;
    int row = blockIdx.x;
    if (t < 128) gl[t] = grid[t];
    if (t < H2_ * 3 + 3) w3s[t] = (t < H2_ * 3) ? W3[t] : b3[t - H2_ * 3];
    float a1v = a1[t], d1v = d1[t];
    float base = a1v * tokpart[(size_t)row * C_ + t] + d1v;
    float wgx = a1v * W1[C_ * H1_ + t];
    float wgy = a1v * W1[(C_ + 1) * H1_ + t];
    __syncthreads();
    for (int n = 0; n < 64; ++n) {
        float v = fmaf(wgy, gl[2 * n + 1], fmaf(wgx, gl[2 * n], base));
        y1[n * 264 + t] = (__bf16)fmaxf(v, 0.f);
    }
    __syncthreads();

    int w = t >> 6, l = t & 63, quad = l >> 4, col = l & 15;
    int c2 = w * 16 + col;
    bf16x8 bfrag[8];
#pragma unroll
    for (int ks = 0; ks < 8; ++ks)
        bfrag[ks] = *(const bf16x8*)(W2p + (((w * 8 + ks) * 64 + l) * 8));
    float b2v = b2[c2], a2v = a2[c2], d2v = d2[c2];
    for (int rt = 0; rt < 4; ++rt) {
        f32x4 acc = {0.f, 0.f, 0.f, 0.f};
#pragma unroll
        for (int ks = 0; ks < 8; ++ks) {
            bf16x8 a = *(const bf16x8*)(&y1[(rt * 16 + col) * 264 + ks * 32 + quad * 8]);
            acc = __builtin_amdgcn_mfma_f32_16x16x32_bf16(a, bfrag[ks], acc, 0, 0, 0);
        }
#pragma unroll
        for (int r = 0; r < 4; ++r) {
            float h = fmaf(a2v, acc[r] + b2v, d2v);
            y2[(rt * 16 + quad * 4 + r) * 65 + c2] = fmaxf(h, 0.f);
        }
    }
    __syncthreads();
    if (t < 192) {                          // t = n*3 + j
        int n = t / 3, j = t - 3 * (t / 3);
        float acc = w3s[H2_ * 3 + j];
        for (int k = 0; k < H2_; ++k)
            acc += y2[n * 65 + k] * w3s[k * 3 + j];
        fine[(size_t)row * 192 + t] = coarse[row * 3 + j] + acc;
    }
}

// ---------------- host launcher -----------------------------------------------------
extern "C" void kernel_launch(void* const* d_in, const int* in_sizes, int n_in,
                              void* d_out, int out_size, void* d_ws, size_t ws_size,
                              hipStream_t stream) {
    (void)in_sizes; (void)n_in; (void)out_size; (void)ws_size;
    const float* tokens = (const float*)d_in[0];
    const float* grid   = (const float*)d_in[1];
    const float* Wc     = (const float*)d_in[2];
    const float* bc     = (const float*)d_in[3];
    const float* W1     = (const float*)d_in[4];
    const float* gamma1 = (const float*)d_in[6];
    const float* beta1  = (const float*)d_in[7];
    const float* W2     = (const float*)d_in[8];
    const float* b2     = (const float*)d_in[9];
    const float* gamma2 = (const float*)d_in[10];
    const float* beta2  = (const float*)d_in[11];
    const float* W3     = (const float*)d_in[12];
    const float* b3     = (const float*)d_in[13];

    char* ws = (char*)d_ws;
    float*  tokpart = (float*)(ws);                      // 16,777,216 B
    __bf16* W1p     = (__bf16*)(ws + 16777216);          //    131,072 B
    __bf16* W2p     = (__bf16*)(ws + 16908288);          //     32,768 B
    float*  p1s     = (float*)(ws + 16941056);           //     32,768 B
    float*  p1q     = (float*)(ws + 16973824);           //     32,768 B
    float*  p2s     = (float*)(ws + 17006592);           //     16,384 B
    float*  p2q     = (float*)(ws + 17022976);           //     16,384 B
    float*  a1      = (float*)(ws + 17039360);
    float*  d1      = (float*)(ws + 17040384);
    float*  a2      = (float*)(ws + 17041408);
    float*  d2      = (float*)(ws + 17041664);

    float* coarse = (float*)d_out;                       // 49,152 floats
    float* fine   = (float*)d_out + (size_t)ROWS * 3;    // 3,145,728 floats

    k0_pack<<<320, 256, 0, stream>>>(W1, W2, W1p, W2p, p1s);
    k1a<<<ROWS / 64, 256, 0, stream>>>(tokens, Wc, bc, W1p, tokpart, coarse, p1s, p1q);
    k1b<<<1, 256, 0, stream>>>(grid, W1, gamma1, beta1, p1s, p1q, a1, d1);
    k2<<<ROWS, 256, 0, stream>>>(tokpart, grid, W1, W2p, a1, d1, b2, p2s, p2q);
    k2b<<<1, 64, 0, stream>>>(p2s, p2q, gamma2, beta2, a2, d2);
    k3<<<ROWS, 256, 0, stream>>>(tokpart, grid, W1, W2p, a1, d1, b2, a2, d2, W3, b3, coarse, fine);
}

// Round 2
// 263.025 us; speedup vs baseline: 1.0978x; 1.0978x over previous
//
#include <hip/hip_runtime.h>
#include <hip/hip_bf16.h>

#define ROWS 16384
#define C_   256
#define H1_  256
#define H2_  64
#define EPSN 1e-5f

typedef __bf16 bf16x8 __attribute__((ext_vector_type(8)));
typedef float  f32x4  __attribute__((ext_vector_type(4)));

// ---------------- K0: pack W1/W2/W3 into MFMA B-fragment order, zero partial buffers
// B-frag (16x16x32 bf16): lane l supplies B[k=(l>>4)*8+j][col=l&15], j=0..7.
__global__ __launch_bounds__(256) void k0_pack(const float* __restrict__ W1,
                                               const float* __restrict__ W2,
                                               const float* __restrict__ W3,
                                               __bf16* __restrict__ W1p,
                                               __bf16* __restrict__ W2p,
                                               __bf16* __restrict__ W3p,
                                               float* __restrict__ zero_base) {
    int idx = blockIdx.x * 256 + threadIdx.x;   // 0 .. 81919
    if (idx < 65536) {
        int j = idx & 7, l = (idx >> 3) & 63, rest = idx >> 9;
        int ks = rest & 7, ct = (rest >> 3) & 3, w = rest >> 5;
        int k = ks * 32 + ((l >> 4) << 3) + j;
        int c = w * 64 + ct * 16 + (l & 15);
        W1p[idx] = (__bf16)W1[k * H1_ + c];
    } else {
        int i2 = idx - 65536;                   // < 16384
        int j = i2 & 7, l = (i2 >> 3) & 63, rest = i2 >> 9;
        int ks = rest & 7, w = rest >> 3;
        int k = ks * 32 + ((l >> 4) << 3) + j;
        int c2 = w * 16 + (l & 15);
        W2p[i2] = (__bf16)W2[k * H2_ + c2];
    }
    if (idx < 1024) {                           // W3p: K=64, one 16-col chunk (3 valid)
        int j = idx & 7, l = (idx >> 3) & 63, ks = idx >> 9;
        int k = ks * 32 + ((l >> 4) << 3) + j;
        int c = l & 15;
        W3p[idx] = (c < 3) ? (__bf16)W3[k * 3 + c] : (__bf16)0.f;
    }
    if (idx < 24576) zero_base[idx] = 0.0f;     // p1s,p1q,p2s,p2q contiguous
}

// ---------------- KC: coarse = tokens @ Wc + bc  (one wave per row, shuffle reduce)
__global__ __launch_bounds__(256) void kc(const float* __restrict__ tokens,
                                          const float* __restrict__ Wc,
                                          const float* __restrict__ bc,
                                          float* __restrict__ coarse) {
    int t = threadIdx.x, w = t >> 6, l = t & 63;
    int row = blockIdx.x * 4 + w;
    int c0 = l * 4;
    f32x4 tv = *(const f32x4*)(tokens + (size_t)row * C_ + c0);
    f32x4 w0 = *(const f32x4*)(Wc + c0 * 3);
    f32x4 w1 = *(const f32x4*)(Wc + c0 * 3 + 4);
    f32x4 w2 = *(const f32x4*)(Wc + c0 * 3 + 8);
    float wc[12] = {w0[0], w0[1], w0[2], w0[3], w1[0], w1[1], w1[2], w1[3],
                    w2[0], w2[1], w2[2], w2[3]};
    float p[3] = {0.f, 0.f, 0.f};
#pragma unroll
    for (int i = 0; i < 4; ++i)
#pragma unroll
        for (int j = 0; j < 3; ++j) p[j] = fmaf(tv[i], wc[i * 3 + j], p[j]);
#pragma unroll
    for (int off = 1; off < 64; off <<= 1) {
#pragma unroll
        for (int j = 0; j < 3; ++j) p[j] += __shfl_xor(p[j], off, 64);
    }
    if (l == 0) {
#pragma unroll
        for (int j = 0; j < 3; ++j) coarse[row * 3 + j] = p[j] + bc[j];
    }
}

// ---------------- K1a: tokpart = tokens @ W1[:C] ; per-channel stats ----------------
// 1024 blocks x 16 rows. Wave w owns col-quarter w*64..w*64+63, B persistent in VGPRs.
// Each wave stages its own bf16 copy of the A tile (no barriers).
__global__ __launch_bounds__(256, 2) void k1a(const float* __restrict__ tokens,
                                              const __bf16* __restrict__ W1p,
                                              float* __restrict__ tokpart,
                                              float* __restrict__ p1s,
                                              float* __restrict__ p1q) {
    __shared__ __align__(16) __bf16 Al[4][16 * 264];
    int t = threadIdx.x, w = t >> 6, l = t & 63;
    int quad = l >> 4, col = l & 15;
    int rowbase = blockIdx.x * 16;
    int slot = blockIdx.x & 31;

    bf16x8 bfr[32];
#pragma unroll
    for (int ct = 0; ct < 4; ++ct)
#pragma unroll
        for (int ks = 0; ks < 8; ++ks)
            bfr[ct * 8 + ks] = *(const bf16x8*)(W1p + ((((w * 4 + ct) * 8 + ks) * 64 + l) * 8));

    // stage A (own copy): lane covers 8 channels x 8 rows
    int c0 = (l & 31) * 8, rh = l >> 5;
#pragma unroll
    for (int i = 0; i < 8; ++i) {
        int r = rh + 2 * i;
        const float* src = tokens + (size_t)(rowbase + r) * C_ + c0;
        f32x4 t0 = *(const f32x4*)(src);
        f32x4 t1 = *(const f32x4*)(src + 4);
        bf16x8 v;
#pragma unroll
        for (int e = 0; e < 4; ++e) { v[e] = (__bf16)t0[e]; v[e + 4] = (__bf16)t1[e]; }
        *(bf16x8*)(&Al[w][r * 264 + c0]) = v;
    }

    bf16x8 af[8];
#pragma unroll
    for (int ks = 0; ks < 8; ++ks)
        af[ks] = *(const bf16x8*)(&Al[w][col * 264 + ks * 32 + quad * 8]);

#pragma unroll
    for (int ct = 0; ct < 4; ++ct) {
        f32x4 acc = {0.f, 0.f, 0.f, 0.f};
#pragma unroll
        for (int ks = 0; ks < 8; ++ks)
            acc = __builtin_amdgcn_mfma_f32_16x16x32_bf16(af[ks], bfr[ct * 8 + ks], acc, 0, 0, 0);
        int c = w * 64 + ct * 16 + col;
        float s = 0.f, q = 0.f;
#pragma unroll
        for (int rr = 0; rr < 4; ++rr) {
            float v = acc[rr];
            tokpart[(size_t)(rowbase + quad * 4 + rr) * C_ + c] = v;
            s += v; q += v * v;
        }
        s += __shfl_xor(s, 16, 64); s += __shfl_xor(s, 32, 64);
        q += __shfl_xor(q, 16, 64); q += __shfl_xor(q, 32, 64);
        if (l < 16) {
            atomicAdd(p1s + slot * C_ + w * 64 + ct * 16 + l, s);
            atomicAdd(p1q + slot * C_ + w * 64 + ct * 16 + l, q);
        }
    }
}

// ---------------- K1b: BN1 params (var decomposition over product set) --------------
__global__ void k1b(const float* __restrict__ grid, const float* __restrict__ W1,
                    const float* __restrict__ gamma1, const float* __restrict__ beta1,
                    const float* __restrict__ p1s, const float* __restrict__ p1q,
                    float* __restrict__ a1o, float* __restrict__ d1o) {
    int t = threadIdx.x;                    // 256 = channel
    float S = 0.f, Qq = 0.f;
    for (int s = 0; s < 32; ++s) { S += p1s[s * C_ + t]; Qq += p1q[s * C_ + t]; }
    float mean_t = S / (float)ROWS;
    float var_t = Qq / (float)ROWS - mean_t * mean_t;
    float wx = W1[C_ * H1_ + t];
    float wy = W1[(C_ + 1) * H1_ + t];
    float mg = 0.f, qg = 0.f;
    for (int n = 0; n < 64; ++n) {
        float gv = grid[2 * n] * wx + grid[2 * n + 1] * wy;
        mg += gv; qg += gv * gv;
    }
    mg *= (1.f / 64.f);
    float var_g = qg * (1.f / 64.f) - mg * mg;
    float a1 = gamma1[t] * rsqrtf(var_t + var_g + EPSN);
    a1o[t] = a1;
    d1o[t] = beta1[t] - a1 * (mean_t + mg);
}

// ---------------- K2: pass 1 — h2pre stats. Wave = 1 rt-tile x 4 chunks, no barriers.
__global__ __launch_bounds__(256, 2) void k2(const float* __restrict__ tokpart,
                                             const float* __restrict__ grid,
                                             const float* __restrict__ W1,
                                             const __bf16* __restrict__ W2p,
                                             const float* __restrict__ a1,
                                             const float* __restrict__ d1,
                                             const float* __restrict__ b2,
                                             float* __restrict__ p2s,
                                             float* __restrict__ p2q) {
    __shared__ __align__(16) __bf16 y1[64 * 264];
    int t = threadIdx.x, w = t >> 6, l = t & 63;
    int quad = l >> 4, col = l & 15;
    int c0 = (l & 31) * 8, nh = l >> 5;

    bf16x8 bfr[32];
#pragma unroll
    for (int ck = 0; ck < 4; ++ck)
#pragma unroll
        for (int ks = 0; ks < 8; ++ks)
            bfr[ck * 8 + ks] = *(const bf16x8*)(W2p + (((ck * 8 + ks) * 64 + l) * 8));

    float A_[8];
#pragma unroll
    for (int j = 0; j < 8; ++j) A_[j] = grid[2 * j + 1];
    float wgx[8], wgy[8];
    {
        f32x4 a0 = *(const f32x4*)(a1 + c0), a1h = *(const f32x4*)(a1 + c0 + 4);
        f32x4 x0 = *(const f32x4*)(W1 + C_ * H1_ + c0), x1 = *(const f32x4*)(W1 + C_ * H1_ + c0 + 4);
        f32x4 y0 = *(const f32x4*)(W1 + (C_ + 1) * H1_ + c0), yh = *(const f32x4*)(W1 + (C_ + 1) * H1_ + c0 + 4);
#pragma unroll
        for (int e = 0; e < 4; ++e) {
            wgx[e] = a0[e] * x0[e]; wgx[e + 4] = a1h[e] * x1[e];
            wgy[e] = a0[e] * y0[e]; wgy[e + 4] = a1h[e] * yh[e];
        }
    }
    float b2v[4];
#pragma unroll
    for (int ck = 0; ck < 4; ++ck) b2v[ck] = b2[ck * 16 + col];

    float s[4] = {0.f, 0.f, 0.f, 0.f}, q[4] = {0.f, 0.f, 0.f, 0.f};

#pragma unroll 1
    for (int r8 = 0; r8 < 8; ++r8) {
        int row = blockIdx.x * 8 + r8;
        float base[8];
        {
            f32x4 t0 = *(const f32x4*)(tokpart + (size_t)row * C_ + c0);
            f32x4 t1 = *(const f32x4*)(tokpart + (size_t)row * C_ + c0 + 4);
            f32x4 av0 = *(const f32x4*)(a1 + c0), av1 = *(const f32x4*)(a1 + c0 + 4);
            f32x4 dv0 = *(const f32x4*)(d1 + c0), dv1 = *(const f32x4*)(d1 + c0 + 4);
#pragma unroll
            for (int e = 0; e < 4; ++e) {
                base[e] = fmaf(av0[e], t0[e], dv0[e]);
                base[e + 4] = fmaf(av1[e], t1[e], dv1[e]);
            }
        }
        // stage this wave's 16 n-rows
#pragma unroll
        for (int ih = 0; ih < 2; ++ih) {
            float ax = A_[2 * w + ih];      // ix = n>>3 = 2w+ih
            float tc[8];
#pragma unroll
            for (int e = 0; e < 8; ++e) tc[e] = fmaf(wgx[e], ax, base[e]);
#pragma unroll
            for (int kk = 0; kk < 4; ++kk) {
                int iy = nh + 2 * kk;
                float ay = A_[iy];
                int n = w * 16 + ih * 8 + iy;
                bf16x8 v;
#pragma unroll
                for (int e = 0; e < 8; ++e)
                    v[e] = (__bf16)fmaxf(fmaf(wgy[e], ay, tc[e]), 0.f);
                *(bf16x8*)(&y1[n * 264 + c0]) = v;
            }
        }
        // MFMA on own rows
        bf16x8 af[8];
#pragma unroll
        for (int ks = 0; ks < 8; ++ks)
            af[ks] = *(const bf16x8*)(&y1[(w * 16 + col) * 264 + ks * 32 + quad * 8]);
#pragma unroll
        for (int ck = 0; ck < 4; ++ck) {
            f32x4 acc = {0.f, 0.f, 0.f, 0.f};
#pragma unroll
            for (int ks = 0; ks < 8; ++ks)
                acc = __builtin_amdgcn_mfma_f32_16x16x32_bf16(af[ks], bfr[ck * 8 + ks], acc, 0, 0, 0);
#pragma unroll
            for (int rr = 0; rr < 4; ++rr) {
                float h = acc[rr] + b2v[ck];
                s[ck] += h; q[ck] += h * h;
            }
        }
    }
    int slot = blockIdx.x & 63;
#pragma unroll
    for (int ck = 0; ck < 4; ++ck) {
        float sv = s[ck], qv = q[ck];
        sv += __shfl_xor(sv, 16, 64); sv += __shfl_xor(sv, 32, 64);
        qv += __shfl_xor(qv, 16, 64); qv += __shfl_xor(qv, 32, 64);
        if (l < 16) {
            atomicAdd(p2s + slot * H2_ + ck * 16 + l, sv);
            atomicAdd(p2q + slot * H2_ + ck * 16 + l, qv);
        }
    }
}

// ---------------- K2b: BN2 params, fold b2 ------------------------------------------
__global__ void k2b(const float* __restrict__ p2s, const float* __restrict__ p2q,
                    const float* __restrict__ gamma2, const float* __restrict__ beta2,
                    const float* __restrict__ b2,
                    float* __restrict__ a2o, float* __restrict__ d2o) {
    int t = threadIdx.x;                    // 64 = channel
    float S = 0.f, Qq = 0.f;
    for (int s = 0; s < 64; ++s) { S += p2s[s * H2_ + t]; Qq += p2q[s * H2_ + t]; }
    const float invN = 1.f / ((float)ROWS * 64.f);
    float mean = S * invN;
    float var = Qq * invN - mean * mean;
    float a2 = gamma2[t] * rsqrtf(var + EPSN);
    a2o[t] = a2;
    d2o[t] = beta2[t] - a2 * (mean - b2[t]); // d2' folds +b2 (acc excludes b2)
}

// ---------------- K3: pass 2 — recompute, BN2+ReLU, y2@W3 via 2nd MFMA, store fine --
__global__ __launch_bounds__(256, 2) void k3(const float* __restrict__ tokpart,
                                             const float* __restrict__ grid,
                                             const float* __restrict__ W1,
                                             const __bf16* __restrict__ W2p,
                                             const float* __restrict__ a1,
                                             const float* __restrict__ d1,
                                             const __bf16* __restrict__ W3p,
                                             const float* __restrict__ a2,
                                             const float* __restrict__ d2p,
                                             const float* __restrict__ b3,
                                             const float* __restrict__ coarse,
                                             float* __restrict__ fine) {
    __shared__ __align__(16) __bf16 y1[64 * 264];
    __shared__ __align__(16) __bf16 y2l[4][16 * 72];
    int t = threadIdx.x, w = t >> 6, l = t & 63;
    int quad = l >> 4, col = l & 15;
    int c0 = (l & 31) * 8, nh = l >> 5;

    bf16x8 bfr[32];
#pragma unroll
    for (int ck = 0; ck < 4; ++ck)
#pragma unroll
        for (int ks = 0; ks < 8; ++ks)
            bfr[ck * 8 + ks] = *(const bf16x8*)(W2p + (((ck * 8 + ks) * 64 + l) * 8));
    bf16x8 wfr[2];
#pragma unroll
    for (int ks = 0; ks < 2; ++ks)
        wfr[ks] = *(const bf16x8*)(W3p + ((ks * 64 + l) * 8));

    float A_[8];
#pragma unroll
    for (int j = 0; j < 8; ++j) A_[j] = grid[2 * j + 1];
    float wgx[8], wgy[8];
    {
        f32x4 a0 = *(const f32x4*)(a1 + c0), a1h = *(const f32x4*)(a1 + c0 + 4);
        f32x4 x0 = *(const f32x4*)(W1 + C_ * H1_ + c0), x1 = *(const f32x4*)(W1 + C_ * H1_ + c0 + 4);
        f32x4 y0 = *(const f32x4*)(W1 + (C_ + 1) * H1_ + c0), yh = *(const f32x4*)(W1 + (C_ + 1) * H1_ + c0 + 4);
#pragma unroll
        for (int e = 0; e < 4; ++e) {
            wgx[e] = a0[e] * x0[e]; wgx[e + 4] = a1h[e] * x1[e];
            wgy[e] = a0[e] * y0[e]; wgy[e + 4] = a1h[e] * yh[e];
        }
    }
    float a2v[4], d2v[4];
#pragma unroll
    for (int ck = 0; ck < 4; ++ck) {
        a2v[ck] = a2[ck * 16 + col];
        d2v[ck] = d2p[ck * 16 + col];
    }
    float b3v = (col < 3) ? b3[col] : 0.f;

#pragma unroll 1
    for (int r8 = 0; r8 < 8; ++r8) {
        int row = blockIdx.x * 8 + r8;
        float base[8];
        {
            f32x4 t0 = *(const f32x4*)(tokpart + (size_t)row * C_ + c0);
            f32x4 t1 = *(const f32x4*)(tokpart + (size_t)row * C_ + c0 + 4);
            f32x4 av0 = *(const f32x4*)(a1 + c0), av1 = *(const f32x4*)(a1 + c0 + 4);
            f32x4 dv0 = *(const f32x4*)(d1 + c0), dv1 = *(const f32x4*)(d1 + c0 + 4);
#pragma unroll
            for (int e = 0; e < 4; ++e) {
                base[e] = fmaf(av0[e], t0[e], dv0[e]);
                base[e + 4] = fmaf(av1[e], t1[e], dv1[e]);
            }
        }
#pragma unroll
        for (int ih = 0; ih < 2; ++ih) {
            float ax = A_[2 * w + ih];
            float tc[8];
#pragma unroll
            for (int e = 0; e < 8; ++e) tc[e] = fmaf(wgx[e], ax, base[e]);
#pragma unroll
            for (int kk = 0; kk < 4; ++kk) {
                int iy = nh + 2 * kk;
                float ay = A_[iy];
                int n = w * 16 + ih * 8 + iy;
                bf16x8 v;
#pragma unroll
                for (int e = 0; e < 8; ++e)
                    v[e] = (__bf16)fmaxf(fmaf(wgy[e], ay, tc[e]), 0.f);
                *(bf16x8*)(&y1[n * 264 + c0]) = v;
            }
        }
        bf16x8 af[8];
#pragma unroll
        for (int ks = 0; ks < 8; ++ks)
            af[ks] = *(const bf16x8*)(&y1[(w * 16 + col) * 264 + ks * 32 + quad * 8]);
        f32x4 accs[4];
#pragma unroll
        for (int ck = 0; ck < 4; ++ck) {
            f32x4 acc = {0.f, 0.f, 0.f, 0.f};
#pragma unroll
            for (int ks = 0; ks < 8; ++ks)
                acc = __builtin_amdgcn_mfma_f32_16x16x32_bf16(af[ks], bfr[ck * 8 + ks], acc, 0, 0, 0);
            accs[ck] = acc;
        }
        // BN2 + ReLU -> y2 (bf16) into per-wave LDS region, A-layout
#pragma unroll
        for (int ck = 0; ck < 4; ++ck)
#pragma unroll
            for (int rr = 0; rr < 4; ++rr) {
                float y = fmaxf(fmaf(a2v[ck], accs[ck][rr], d2v[ck]), 0.f);
                y2l[w][(quad * 4 + rr) * 72 + ck * 16 + col] = (__bf16)y;
            }
        bf16x8 af2[2];
#pragma unroll
        for (int ks = 0; ks < 2; ++ks)
            af2[ks] = *(const bf16x8*)(&y2l[w][col * 72 + ks * 32 + quad * 8]);
        f32x4 d2acc = {0.f, 0.f, 0.f, 0.f};
        d2acc = __builtin_amdgcn_mfma_f32_16x16x32_bf16(af2[0], wfr[0], d2acc, 0, 0, 0);
        d2acc = __builtin_amdgcn_mfma_f32_16x16x32_bf16(af2[1], wfr[1], d2acc, 0, 0, 0);
        float cj = (col < 3) ? coarse[row * 3 + col] + b3v : 0.f;
        if (col < 3) {
#pragma unroll
            for (int rr = 0; rr < 4; ++rr) {
                int n = w * 16 + quad * 4 + rr;
                fine[((size_t)row * 64 + n) * 3 + col] = d2acc[rr] + cj;
            }
        }
    }
}

// ---------------- host launcher -----------------------------------------------------
extern "C" void kernel_launch(void* const* d_in, const int* in_sizes, int n_in,
                              void* d_out, int out_size, void* d_ws, size_t ws_size,
                              hipStream_t stream) {
    (void)in_sizes; (void)n_in; (void)out_size; (void)ws_size;
    const float* tokens = (const float*)d_in[0];
    const float* grid   = (const float*)d_in[1];
    const float* Wc     = (const float*)d_in[2];
    const float* bc     = (const float*)d_in[3];
    const float* W1     = (const float*)d_in[4];
    const float* gamma1 = (const float*)d_in[6];
    const float* beta1  = (const float*)d_in[7];
    const float* W2     = (const float*)d_in[8];
    const float* b2     = (const float*)d_in[9];
    const float* gamma2 = (const float*)d_in[10];
    const float* beta2  = (const float*)d_in[11];
    const float* W3     = (const float*)d_in[12];
    const float* b3     = (const float*)d_in[13];

    char* ws = (char*)d_ws;
    float*  tokpart = (float*)(ws);                      // 16,777,216 B
    __bf16* W1p     = (__bf16*)(ws + 16777216);          //    131,072 B
    __bf16* W2p     = (__bf16*)(ws + 16908288);          //     32,768 B
    float*  p1s     = (float*)(ws + 16941056);           //     32,768 B
    float*  p1q     = (float*)(ws + 16973824);           //     32,768 B
    float*  p2s     = (float*)(ws + 17006592);           //     16,384 B
    float*  p2q     = (float*)(ws + 17022976);           //     16,384 B
    float*  a1      = (float*)(ws + 17039360);           //      1,024 B
    float*  d1      = (float*)(ws + 17040384);           //      1,024 B
    float*  a2      = (float*)(ws + 17041408);           //        256 B
    float*  d2p     = (float*)(ws + 17041664);           //        256 B
    __bf16* W3p     = (__bf16*)(ws + 17041920);          //      2,048 B

    float* coarse = (float*)d_out;                       // 49,152 floats
    float* fine   = (float*)d_out + (size_t)ROWS * 3;    // 3,145,728 floats

    k0_pack<<<320, 256, 0, stream>>>(W1, W2, W3, W1p, W2p, W3p, p1s);
    kc<<<ROWS / 4, 256, 0, stream>>>(tokens, Wc, bc, coarse);
    k1a<<<ROWS / 16, 256, 0, stream>>>(tokens, W1p, tokpart, p1s, p1q);
    k1b<<<1, 256, 0, stream>>>(grid, W1, gamma1, beta1, p1s, p1q, a1, d1);
    k2<<<ROWS / 8, 256, 0, stream>>>(tokpart, grid, W1, W2p, a1, d1, b2, p2s, p2q);
    k2b<<<1, 64, 0, stream>>>(p2s, p2q, gamma2, beta2, b2, a2, d2p);
    k3<<<ROWS / 8, 256, 0, stream>>>(tokpart, grid, W1, W2p, a1, d1, W3p, a2, d2p, b3, coarse, fine);
}

// Round 3
// 227.593 us; speedup vs baseline: 1.2687x; 1.1557x over previous
//
#include <hip/hip_runtime.h>
#include <hip/hip_bf16.h>

#define ROWS 16384
#define C_   256
#define H1_  256
#define H2_  64
#define EPSN 1e-5f

typedef __bf16 bf16x8 __attribute__((ext_vector_type(8)));
typedef __bf16 bf16x4 __attribute__((ext_vector_type(4)));
typedef float  f32x4  __attribute__((ext_vector_type(4)));

// ---------------- K0: pack W1/W2/W3 into MFMA fragment order, zero partial buffers --
// Frag layout (16x16x32 bf16, A and B are index-symmetric): lane l supplies
// element [k=(l>>4)*8+j][mn=l&15], j=0..7.
__global__ __launch_bounds__(256) void k0_pack(const float* __restrict__ W1,
                                               const float* __restrict__ W2,
                                               const float* __restrict__ W3,
                                               __bf16* __restrict__ W1p,
                                               __bf16* __restrict__ W2p,
                                               __bf16* __restrict__ W3p,
                                               float* __restrict__ zero_base) {
    int idx = blockIdx.x * 256 + threadIdx.x;   // 0 .. 81919
    if (idx < 65536) {
        int j = idx & 7, l = (idx >> 3) & 63, rest = idx >> 9;
        int ks = rest & 7, CT = rest >> 3;      // CT = 16-col chunk 0..15
        int k = ks * 32 + ((l >> 4) << 3) + j;
        int c = CT * 16 + (l & 15);
        W1p[idx] = (__bf16)W1[k * H1_ + c];
    } else {
        int i2 = idx - 65536;                   // < 16384
        int j = i2 & 7, l = (i2 >> 3) & 63, rest = i2 >> 9;
        int ks = rest & 7, CK = rest >> 3;      // CK 0..3
        int k = ks * 32 + ((l >> 4) << 3) + j;
        int c2 = CK * 16 + (l & 15);
        W2p[i2] = (__bf16)W2[k * H2_ + c2];
    }
    if (idx < 1024) {                           // W3p: K=64, one 16-col chunk (3 valid)
        int j = idx & 7, l = (idx >> 3) & 63, ks = idx >> 9;
        int k = ks * 32 + ((l >> 4) << 3) + j;
        int c = l & 15;
        W3p[idx] = (c < 3) ? (__bf16)W3[k * 3 + c] : (__bf16)0.f;
    }
    if (idx < 24576) zero_base[idx] = 0.0f;     // p1s,p1q,p2s,p2q contiguous
}

// ---------------- KC: coarse = tokens @ Wc + bc  (one wave per row, shuffle reduce)
__global__ __launch_bounds__(256) void kc(const float* __restrict__ tokens,
                                          const float* __restrict__ Wc,
                                          const float* __restrict__ bc,
                                          float* __restrict__ coarse) {
    int t = threadIdx.x, w = t >> 6, l = t & 63;
    int row = blockIdx.x * 4 + w;
    int c0 = l * 4;
    f32x4 tv = *(const f32x4*)(tokens + (size_t)row * C_ + c0);
    f32x4 w0 = *(const f32x4*)(Wc + c0 * 3);
    f32x4 w1 = *(const f32x4*)(Wc + c0 * 3 + 4);
    f32x4 w2 = *(const f32x4*)(Wc + c0 * 3 + 8);
    float wc[12] = {w0[0], w0[1], w0[2], w0[3], w1[0], w1[1], w1[2], w1[3],
                    w2[0], w2[1], w2[2], w2[3]};
    float p[3] = {0.f, 0.f, 0.f};
#pragma unroll
    for (int i = 0; i < 4; ++i)
#pragma unroll
        for (int j = 0; j < 3; ++j) p[j] = fmaf(tv[i], wc[i * 3 + j], p[j]);
#pragma unroll
    for (int off = 1; off < 64; off <<= 1) {
#pragma unroll
        for (int j = 0; j < 3; ++j) p[j] += __shfl_xor(p[j], off, 64);
    }
    if (l == 0) {
#pragma unroll
        for (int j = 0; j < 3; ++j) coarse[row * 3 + j] = p[j] + bc[j];
    }
}

// ---------------- K1a: tokpart = tokens @ W1[:C] ; per-channel stats ----------------
// 2048 blocks: rowgroup = bx>>1 (16 rows), colhalf = bx&1 (128 cols).
// Wave w owns 32 cols (2 chunks) -> 16 B-frags (64 VGPR). One barrier.
__global__ __launch_bounds__(256) void k1a(const float* __restrict__ tokens,
                                           const __bf16* __restrict__ W1p,
                                           float* __restrict__ tokpart,
                                           float* __restrict__ p1s,
                                           float* __restrict__ p1q) {
    __shared__ __align__(16) __bf16 Al[16 * 264];
    int t = threadIdx.x, w = t >> 6, l = t & 63;
    int quad = l >> 4, col = l & 15;
    int rowbase = (blockIdx.x >> 1) * 16;
    int colhalf = blockIdx.x & 1;
    int slot = blockIdx.x & 31;

    bf16x8 bfr[16];
#pragma unroll
    for (int ctl = 0; ctl < 2; ++ctl)
#pragma unroll
        for (int ks = 0; ks < 8; ++ks) {
            int CT = colhalf * 8 + w * 2 + ctl;
            bfr[ctl * 8 + ks] = *(const bf16x8*)(W1p + (((CT * 8 + ks) * 64 + l) * 8));
        }

    // stage A: thread t covers row = t>>4, cols (t&15)*16..+16
    {
        int r = t >> 4, cb = (t & 15) * 16;
        const float* src = tokens + (size_t)(rowbase + r) * C_ + cb;
        f32x4 t0 = *(const f32x4*)(src);
        f32x4 t1 = *(const f32x4*)(src + 4);
        f32x4 t2 = *(const f32x4*)(src + 8);
        f32x4 t3 = *(const f32x4*)(src + 12);
        bf16x8 v0, v1;
#pragma unroll
        for (int e = 0; e < 4; ++e) {
            v0[e] = (__bf16)t0[e]; v0[e + 4] = (__bf16)t1[e];
            v1[e] = (__bf16)t2[e]; v1[e + 4] = (__bf16)t3[e];
        }
        *(bf16x8*)(&Al[r * 264 + cb]) = v0;
        *(bf16x8*)(&Al[r * 264 + cb + 8]) = v1;
    }
    __syncthreads();

    bf16x8 af[8];
#pragma unroll
    for (int ks = 0; ks < 8; ++ks)
        af[ks] = *(const bf16x8*)(&Al[col * 264 + ks * 32 + quad * 8]);

#pragma unroll
    for (int ctl = 0; ctl < 2; ++ctl) {
        f32x4 acc = {0.f, 0.f, 0.f, 0.f};
#pragma unroll
        for (int ks = 0; ks < 8; ++ks)
            acc = __builtin_amdgcn_mfma_f32_16x16x32_bf16(af[ks], bfr[ctl * 8 + ks], acc, 0, 0, 0);
        int c = colhalf * 128 + w * 32 + ctl * 16 + col;
        float s = 0.f, q = 0.f;
#pragma unroll
        for (int rr = 0; rr < 4; ++rr) {
            float v = acc[rr];
            tokpart[(size_t)(rowbase + quad * 4 + rr) * C_ + c] = v;
            s += v; q += v * v;
        }
        s += __shfl_xor(s, 16, 64); s += __shfl_xor(s, 32, 64);
        q += __shfl_xor(q, 16, 64); q += __shfl_xor(q, 32, 64);
        if (l < 16) {
            int cc = colhalf * 128 + w * 32 + ctl * 16 + l;
            atomicAdd(p1s + slot * C_ + cc, s);
            atomicAdd(p1q + slot * C_ + cc, q);
        }
    }
}

// ---------------- K1b: BN1 params (var decomposition over product set) --------------
__global__ void k1b(const float* __restrict__ grid, const float* __restrict__ W1,
                    const float* __restrict__ gamma1, const float* __restrict__ beta1,
                    const float* __restrict__ p1s, const float* __restrict__ p1q,
                    float* __restrict__ a1o, float* __restrict__ d1o) {
    int t = threadIdx.x;                    // 256 = channel
    float S = 0.f, Qq = 0.f;
    for (int s = 0; s < 32; ++s) { S += p1s[s * C_ + t]; Qq += p1q[s * C_ + t]; }
    float mean_t = S / (float)ROWS;
    float var_t = Qq / (float)ROWS - mean_t * mean_t;
    float wx = W1[C_ * H1_ + t];
    float wy = W1[(C_ + 1) * H1_ + t];
    float mg = 0.f, qg = 0.f;
    for (int n = 0; n < 64; ++n) {
        float gv = grid[2 * n] * wx + grid[2 * n + 1] * wy;
        mg += gv; qg += gv * gv;
    }
    mg *= (1.f / 64.f);
    float var_g = qg * (1.f / 64.f) - mg * mg;
    float a1 = gamma1[t] * rsqrtf(var_t + var_g + EPSN);
    a1o[t] = a1;
    d1o[t] = beta1[t] - a1 * (mean_t + mg);
}

// ---------------- K2: pass 1 — BN2 stats. 2x2 wave tiling, 16 B-frags ---------------
__global__ __launch_bounds__(256) void k2(const float* __restrict__ tokpart,
                                          const float* __restrict__ grid,
                                          const float* __restrict__ W1,
                                          const __bf16* __restrict__ W2p,
                                          const float* __restrict__ a1,
                                          const float* __restrict__ d1,
                                          const float* __restrict__ b2,
                                          float* __restrict__ p2s,
                                          float* __restrict__ p2q) {
    __shared__ __align__(16) __bf16 y1[64 * 264];
    int t = threadIdx.x, w = t >> 6, l = t & 63;
    int quad = l >> 4, col = l & 15;
    int wn = w >> 1, wc = w & 1;
    int c0 = (l & 31) * 8, nh = l >> 5;

    bf16x8 bfr[16];
#pragma unroll
    for (int ck = 0; ck < 2; ++ck)
#pragma unroll
        for (int ks = 0; ks < 8; ++ks)
            bfr[ck * 8 + ks] = *(const bf16x8*)(W2p + ((((wc * 2 + ck) * 8 + ks) * 64 + l) * 8));

    float A_[8];
#pragma unroll
    for (int j = 0; j < 8; ++j) A_[j] = grid[2 * j + 1];
    float wgx[8], wgy[8];
    {
        f32x4 a0 = *(const f32x4*)(a1 + c0), a1h = *(const f32x4*)(a1 + c0 + 4);
        f32x4 x0 = *(const f32x4*)(W1 + C_ * H1_ + c0), x1 = *(const f32x4*)(W1 + C_ * H1_ + c0 + 4);
        f32x4 y0 = *(const f32x4*)(W1 + (C_ + 1) * H1_ + c0), yh = *(const f32x4*)(W1 + (C_ + 1) * H1_ + c0 + 4);
#pragma unroll
        for (int e = 0; e < 4; ++e) {
            wgx[e] = a0[e] * x0[e]; wgx[e + 4] = a1h[e] * x1[e];
            wgy[e] = a0[e] * y0[e]; wgy[e + 4] = a1h[e] * yh[e];
        }
    }
    float b2v[2];
#pragma unroll
    for (int ck = 0; ck < 2; ++ck) b2v[ck] = b2[wc * 32 + ck * 16 + col];

    float s[2] = {0.f, 0.f}, q[2] = {0.f, 0.f};

#pragma unroll 1
    for (int r8 = 0; r8 < 8; ++r8) {
        int row = blockIdx.x * 8 + r8;
        float base[8];
        {
            f32x4 t0 = *(const f32x4*)(tokpart + (size_t)row * C_ + c0);
            f32x4 t1 = *(const f32x4*)(tokpart + (size_t)row * C_ + c0 + 4);
            f32x4 av0 = *(const f32x4*)(a1 + c0), av1 = *(const f32x4*)(a1 + c0 + 4);
            f32x4 dv0 = *(const f32x4*)(d1 + c0), dv1 = *(const f32x4*)(d1 + c0 + 4);
#pragma unroll
            for (int e = 0; e < 4; ++e) {
                base[e] = fmaf(av0[e], t0[e], dv0[e]);
                base[e + 4] = fmaf(av1[e], t1[e], dv1[e]);
            }
        }
        // stage own 16 rows (w*16 ..)
#pragma unroll
        for (int ih = 0; ih < 2; ++ih) {
            float ax = A_[2 * w + ih];
            float tc[8];
#pragma unroll
            for (int e = 0; e < 8; ++e) tc[e] = fmaf(wgx[e], ax, base[e]);
#pragma unroll
            for (int kk = 0; kk < 4; ++kk) {
                int iy = nh + 2 * kk;
                float ay = A_[iy];
                int n = w * 16 + ih * 8 + iy;
                bf16x8 v;
#pragma unroll
                for (int e = 0; e < 8; ++e)
                    v[e] = (__bf16)fmaxf(fmaf(wgy[e], ay, tc[e]), 0.f);
                *(bf16x8*)(&y1[n * 264 + c0]) = v;
            }
        }
        __syncthreads();
#pragma unroll
        for (int rt = 0; rt < 2; ++rt) {
            bf16x8 af[8];
#pragma unroll
            for (int ks = 0; ks < 8; ++ks)
                af[ks] = *(const bf16x8*)(&y1[(wn * 32 + rt * 16 + col) * 264 + ks * 32 + quad * 8]);
#pragma unroll
            for (int ck = 0; ck < 2; ++ck) {
                f32x4 acc = {0.f, 0.f, 0.f, 0.f};
#pragma unroll
                for (int ks = 0; ks < 8; ++ks)
                    acc = __builtin_amdgcn_mfma_f32_16x16x32_bf16(af[ks], bfr[ck * 8 + ks], acc, 0, 0, 0);
#pragma unroll
                for (int rr = 0; rr < 4; ++rr) {
                    float h = acc[rr] + b2v[ck];
                    s[ck] += h; q[ck] += h * h;
                }
            }
        }
        __syncthreads();
    }
    int slot = blockIdx.x & 63;
#pragma unroll
    for (int ck = 0; ck < 2; ++ck) {
        float sv = s[ck], qv = q[ck];
        sv += __shfl_xor(sv, 16, 64); sv += __shfl_xor(sv, 32, 64);
        qv += __shfl_xor(qv, 16, 64); qv += __shfl_xor(qv, 32, 64);
        if (l < 16) {
            atomicAdd(p2s + slot * H2_ + wc * 32 + ck * 16 + l, sv);
            atomicAdd(p2q + slot * H2_ + wc * 32 + ck * 16 + l, qv);
        }
    }
}

// ---------------- K2b: BN2 params, fold b2 ------------------------------------------
__global__ void k2b(const float* __restrict__ p2s, const float* __restrict__ p2q,
                    const float* __restrict__ gamma2, const float* __restrict__ beta2,
                    const float* __restrict__ b2,
                    float* __restrict__ a2o, float* __restrict__ d2o) {
    int t = threadIdx.x;                    // 64 = channel
    float S = 0.f, Qq = 0.f;
    for (int s = 0; s < 64; ++s) { S += p2s[s * H2_ + t]; Qq += p2q[s * H2_ + t]; }
    const float invN = 1.f / ((float)ROWS * 64.f);
    float mean = S * invN;
    float var = Qq * invN - mean * mean;
    float a2 = gamma2[t] * rsqrtf(var + EPSN);
    a2o[t] = a2;
    d2o[t] = beta2[t] - a2 * (mean - b2[t]); // d2' folds +b2 (acc excludes b2)
}

// ---------------- K3: pass 2 — recompute, BN2+ReLU, y2@W3, coalesced fine -----------
// Main MFMA operand-SWAPPED: acc holds h2^T -> lane owns 4 consecutive c2 ->
// y2 staged with ds_write_b64; fine staged in LDS, flushed coalesced.
__global__ __launch_bounds__(256) void k3(const float* __restrict__ tokpart,
                                          const float* __restrict__ grid,
                                          const float* __restrict__ W1,
                                          const __bf16* __restrict__ W2p,
                                          const float* __restrict__ a1,
                                          const float* __restrict__ d1,
                                          const __bf16* __restrict__ W3p,
                                          const float* __restrict__ a2,
                                          const float* __restrict__ d2p,
                                          const float* __restrict__ b3,
                                          const float* __restrict__ coarse,
                                          float* __restrict__ fine) {
    __shared__ __align__(16) __bf16 y1[64 * 264];
    __shared__ __align__(16) __bf16 y2l[64 * 72];
    __shared__ __align__(16) float finebuf[8 * 192];
    int t = threadIdx.x, w = t >> 6, l = t & 63;
    int quad = l >> 4, col = l & 15;
    int wn = w >> 1, wc = w & 1;
    int c0 = (l & 31) * 8, nh = l >> 5;

    bf16x8 bfr[16];
#pragma unroll
    for (int ck = 0; ck < 2; ++ck)
#pragma unroll
        for (int ks = 0; ks < 8; ++ks)
            bfr[ck * 8 + ks] = *(const bf16x8*)(W2p + ((((wc * 2 + ck) * 8 + ks) * 64 + l) * 8));
    bf16x8 wfr[2];
#pragma unroll
    for (int ks = 0; ks < 2; ++ks)
        wfr[ks] = *(const bf16x8*)(W3p + ((ks * 64 + l) * 8));

    float A_[8];
#pragma unroll
    for (int j = 0; j < 8; ++j) A_[j] = grid[2 * j + 1];
    float wgx[8], wgy[8];
    {
        f32x4 a0 = *(const f32x4*)(a1 + c0), a1h = *(const f32x4*)(a1 + c0 + 4);
        f32x4 x0 = *(const f32x4*)(W1 + C_ * H1_ + c0), x1 = *(const f32x4*)(W1 + C_ * H1_ + c0 + 4);
        f32x4 y0 = *(const f32x4*)(W1 + (C_ + 1) * H1_ + c0), yh = *(const f32x4*)(W1 + (C_ + 1) * H1_ + c0 + 4);
#pragma unroll
        for (int e = 0; e < 4; ++e) {
            wgx[e] = a0[e] * x0[e]; wgx[e + 4] = a1h[e] * x1[e];
            wgy[e] = a0[e] * y0[e]; wgy[e + 4] = a1h[e] * yh[e];
        }
    }
    float a2v[8], d2v[8];
#pragma unroll
    for (int ck = 0; ck < 2; ++ck)
#pragma unroll
        for (int rr = 0; rr < 4; ++rr) {
            int c2 = wc * 32 + ck * 16 + quad * 4 + rr;
            a2v[ck * 4 + rr] = a2[c2];
            d2v[ck * 4 + rr] = d2p[c2];
        }
    float b3v = (col < 3) ? b3[col] : 0.f;

#pragma unroll 1
    for (int r8 = 0; r8 < 8; ++r8) {
        int row = blockIdx.x * 8 + r8;
        float base[8];
        {
            f32x4 t0 = *(const f32x4*)(tokpart + (size_t)row * C_ + c0);
            f32x4 t1 = *(const f32x4*)(tokpart + (size_t)row * C_ + c0 + 4);
            f32x4 av0 = *(const f32x4*)(a1 + c0), av1 = *(const f32x4*)(a1 + c0 + 4);
            f32x4 dv0 = *(const f32x4*)(d1 + c0), dv1 = *(const f32x4*)(d1 + c0 + 4);
#pragma unroll
            for (int e = 0; e < 4; ++e) {
                base[e] = fmaf(av0[e], t0[e], dv0[e]);
                base[e + 4] = fmaf(av1[e], t1[e], dv1[e]);
            }
        }
#pragma unroll
        for (int ih = 0; ih < 2; ++ih) {
            float ax = A_[2 * w + ih];
            float tc[8];
#pragma unroll
            for (int e = 0; e < 8; ++e) tc[e] = fmaf(wgx[e], ax, base[e]);
#pragma unroll
            for (int kk = 0; kk < 4; ++kk) {
                int iy = nh + 2 * kk;
                float ay = A_[iy];
                int n = w * 16 + ih * 8 + iy;
                bf16x8 v;
#pragma unroll
                for (int e = 0; e < 8; ++e)
                    v[e] = (__bf16)fmaxf(fmaf(wgy[e], ay, tc[e]), 0.f);
                *(bf16x8*)(&y1[n * 264 + c0]) = v;
            }
        }
        __syncthreads();
#pragma unroll
        for (int rt = 0; rt < 2; ++rt) {
            bf16x8 af[8];
#pragma unroll
            for (int ks = 0; ks < 8; ++ks)
                af[ks] = *(const bf16x8*)(&y1[(wn * 32 + rt * 16 + col) * 264 + ks * 32 + quad * 8]);
#pragma unroll
            for (int ck = 0; ck < 2; ++ck) {
                f32x4 acc = {0.f, 0.f, 0.f, 0.f};
#pragma unroll
                for (int ks = 0; ks < 8; ++ks)
                    acc = __builtin_amdgcn_mfma_f32_16x16x32_bf16(bfr[ck * 8 + ks], af[ks], acc, 0, 0, 0);
                // acc[rr] = h2pre[n = wn*32+rt*16+col][c2 = wc*32+ck*16+quad*4+rr]
                bf16x4 v;
#pragma unroll
                for (int rr = 0; rr < 4; ++rr)
                    v[rr] = (__bf16)fmaxf(fmaf(a2v[ck * 4 + rr], acc[rr], d2v[ck * 4 + rr]), 0.f);
                *(bf16x4*)(&y2l[(wn * 32 + rt * 16 + col) * 72 + wc * 32 + ck * 16 + quad * 4]) = v;
            }
        }
        __syncthreads();
        // second MFMA: wave w handles n-tile w*16 (A = y2 frag, B = W3 frag)
        bf16x8 af2[2];
#pragma unroll
        for (int ks = 0; ks < 2; ++ks)
            af2[ks] = *(const bf16x8*)(&y2l[(w * 16 + col) * 72 + ks * 32 + quad * 8]);
        f32x4 d2acc = {0.f, 0.f, 0.f, 0.f};
        d2acc = __builtin_amdgcn_mfma_f32_16x16x32_bf16(af2[0], wfr[0], d2acc, 0, 0, 0);
        d2acc = __builtin_amdgcn_mfma_f32_16x16x32_bf16(af2[1], wfr[1], d2acc, 0, 0, 0);
        if (col < 3) {
            float cj = coarse[row * 3 + col] + b3v;
#pragma unroll
            for (int rr = 0; rr < 4; ++rr)
                finebuf[r8 * 192 + (w * 16 + quad * 4 + rr) * 3 + col] = d2acc[rr] + cj;
        }
    }
    __syncthreads();
    {
        float* dst = fine + (size_t)blockIdx.x * 1536;
        const f32x4* fb = (const f32x4*)finebuf;
        *(f32x4*)(dst + 4 * t) = fb[t];
        if (t < 128) *(f32x4*)(dst + 1024 + 4 * t) = fb[256 + t];
    }
}

// ---------------- host launcher -----------------------------------------------------
extern "C" void kernel_launch(void* const* d_in, const int* in_sizes, int n_in,
                              void* d_out, int out_size, void* d_ws, size_t ws_size,
                              hipStream_t stream) {
    (void)in_sizes; (void)n_in; (void)out_size; (void)ws_size;
    const float* tokens = (const float*)d_in[0];
    const float* grid   = (const float*)d_in[1];
    const float* Wc     = (const float*)d_in[2];
    const float* bc     = (const float*)d_in[3];
    const float* W1     = (const float*)d_in[4];
    const float* gamma1 = (const float*)d_in[6];
    const float* beta1  = (const float*)d_in[7];
    const float* W2     = (const float*)d_in[8];
    const float* b2     = (const float*)d_in[9];
    const float* gamma2 = (const float*)d_in[10];
    const float* beta2  = (const float*)d_in[11];
    const float* W3     = (const float*)d_in[12];
    const float* b3     = (const float*)d_in[13];

    char* ws = (char*)d_ws;
    float*  tokpart = (float*)(ws);                      // 16,777,216 B
    __bf16* W1p     = (__bf16*)(ws + 16777216);          //    131,072 B
    __bf16* W2p     = (__bf16*)(ws + 16908288);          //     32,768 B
    float*  p1s     = (float*)(ws + 16941056);           //     32,768 B
    float*  p1q     = (float*)(ws + 16973824);           //     32,768 B
    float*  p2s     = (float*)(ws + 17006592);           //     16,384 B
    float*  p2q     = (float*)(ws + 17022976);           //     16,384 B
    float*  a1      = (float*)(ws + 17039360);           //      1,024 B
    float*  d1      = (float*)(ws + 17040384);           //      1,024 B
    float*  a2      = (float*)(ws + 17041408);           //        256 B
    float*  d2p     = (float*)(ws + 17041664);           //        256 B
    __bf16* W3p     = (__bf16*)(ws + 17041920);          //      2,048 B

    float* coarse = (float*)d_out;                       // 49,152 floats
    float* fine   = (float*)d_out + (size_t)ROWS * 3;    // 3,145,728 floats

    k0_pack<<<320, 256, 0, stream>>>(W1, W2, W3, W1p, W2p, W3p, p1s);
    kc<<<ROWS / 4, 256, 0, stream>>>(tokens, Wc, bc, coarse);
    k1a<<<2048, 256, 0, stream>>>(tokens, W1p, tokpart, p1s, p1q);
    k1b<<<1, 256, 0, stream>>>(grid, W1, gamma1, beta1, p1s, p1q, a1, d1);
    k2<<<ROWS / 8, 256, 0, stream>>>(tokpart, grid, W1, W2p, a1, d1, b2, p2s, p2q);
    k2b<<<1, 64, 0, stream>>>(p2s, p2q, gamma2, beta2, b2, a2, d2p);
    k3<<<ROWS / 8, 256, 0, stream>>>(tokpart, grid, W1, W2p, a1, d1, W3p, a2, d2p, b3, coarse, fine);
}

// Round 4
// 212.397 us; speedup vs baseline: 1.3595x; 1.0715x over previous
//
#include <hip/hip_runtime.h>
#include <hip/hip_bf16.h>

#define ROWS 16384
#define C_   256
#define H1_  256
#define H2_  64
#define EPSN 1e-5f

typedef __bf16 bf16x8 __attribute__((ext_vector_type(8)));
typedef __bf16 bf16x4 __attribute__((ext_vector_type(4)));
typedef __bf16 bf16x2 __attribute__((ext_vector_type(2)));
typedef float  f32x4  __attribute__((ext_vector_type(4)));
typedef float  f32x2  __attribute__((ext_vector_type(2)));

__device__ __forceinline__ bf16x2 cvt2(float a, float b) {
#if __has_builtin(__builtin_amdgcn_cvt_pk_bf16_f32)
    return __builtin_bit_cast(bf16x2, __builtin_amdgcn_cvt_pk_bf16_f32(a, b));
#else
    bf16x2 r; r[0] = (__bf16)a; r[1] = (__bf16)b; return r;
#endif
}

// ---------------- K0: pack W1/W2/W3 into MFMA fragment order, zero partial buffers --
__global__ __launch_bounds__(256) void k0_pack(const float* __restrict__ W1,
                                               const float* __restrict__ W2,
                                               const float* __restrict__ W3,
                                               __bf16* __restrict__ W1p,
                                               __bf16* __restrict__ W2p,
                                               __bf16* __restrict__ W3p,
                                               float* __restrict__ zero_base) {
    int idx = blockIdx.x * 256 + threadIdx.x;   // 0 .. 81919
    if (idx < 65536) {
        int j = idx & 7, l = (idx >> 3) & 63, rest = idx >> 9;
        int ks = rest & 7, CT = rest >> 3;
        int k = ks * 32 + ((l >> 4) << 3) + j;
        int c = CT * 16 + (l & 15);
        W1p[idx] = (__bf16)W1[k * H1_ + c];
    } else {
        int i2 = idx - 65536;
        int j = i2 & 7, l = (i2 >> 3) & 63, rest = i2 >> 9;
        int ks = rest & 7, CK = rest >> 3;
        int k = ks * 32 + ((l >> 4) << 3) + j;
        int c2 = CK * 16 + (l & 15);
        W2p[i2] = (__bf16)W2[k * H2_ + c2];
    }
    if (idx < 1024) {
        int j = idx & 7, l = (idx >> 3) & 63, ks = idx >> 9;
        int k = ks * 32 + ((l >> 4) << 3) + j;
        int c = l & 15;
        W3p[idx] = (c < 3) ? (__bf16)W3[k * 3 + c] : (__bf16)0.f;
    }
    if (idx < 24576) zero_base[idx] = 0.0f;     // p1s,p1q,p2s,p2q contiguous
}

// ---------------- shared staging helpers --------------------------------------------
__device__ __forceinline__ void prep_ctx(const float* __restrict__ grid,
                                         const float* __restrict__ W1,
                                         const float* __restrict__ a1p, int c0,
                                         f32x2* wgx2, f32x2* wgy2, float* A_) {
#pragma unroll
    for (int j = 0; j < 8; ++j) A_[j] = grid[2 * j + 1];
    f32x4 a0 = *(const f32x4*)(a1p + c0), a1h = *(const f32x4*)(a1p + c0 + 4);
    f32x4 x0 = *(const f32x4*)(W1 + C_ * H1_ + c0), x1 = *(const f32x4*)(W1 + C_ * H1_ + c0 + 4);
    f32x4 y0 = *(const f32x4*)(W1 + (C_ + 1) * H1_ + c0), yh = *(const f32x4*)(W1 + (C_ + 1) * H1_ + c0 + 4);
    float av[8] = {a0[0], a0[1], a0[2], a0[3], a1h[0], a1h[1], a1h[2], a1h[3]};
    float wx[8] = {x0[0], x0[1], x0[2], x0[3], x1[0], x1[1], x1[2], x1[3]};
    float wy[8] = {y0[0], y0[1], y0[2], y0[3], yh[0], yh[1], yh[2], yh[3]};
#pragma unroll
    for (int e = 0; e < 4; ++e) {
        wgx2[e][0] = av[2 * e] * wx[2 * e];     wgx2[e][1] = av[2 * e + 1] * wx[2 * e + 1];
        wgy2[e][0] = av[2 * e] * wy[2 * e];     wgy2[e][1] = av[2 * e + 1] * wy[2 * e + 1];
    }
}

// stage this wave's 16 n-rows of y1 (relu(a1*tok + a1*grid + d1)) into LDS (stride 264)
__device__ __forceinline__ void stage16(__bf16* __restrict__ y1, int w, int c0, int nh,
                                        const float* __restrict__ a1p,
                                        const float* __restrict__ d1p,
                                        const f32x2* wgx2, const f32x2* wgy2,
                                        const float* A_,
                                        const float* __restrict__ tokrow) {
    f32x4 t0 = *(const f32x4*)(tokrow + c0);
    f32x4 t1 = *(const f32x4*)(tokrow + c0 + 4);
    f32x4 a0 = *(const f32x4*)(a1p + c0), a1h = *(const f32x4*)(a1p + c0 + 4);
    f32x4 d0 = *(const f32x4*)(d1p + c0), d1h = *(const f32x4*)(d1p + c0 + 4);
    f32x2 base2[4];
    base2[0][0] = fmaf(a0[0], t0[0], d0[0]);  base2[0][1] = fmaf(a0[1], t0[1], d0[1]);
    base2[1][0] = fmaf(a0[2], t0[2], d0[2]);  base2[1][1] = fmaf(a0[3], t0[3], d0[3]);
    base2[2][0] = fmaf(a1h[0], t1[0], d1h[0]); base2[2][1] = fmaf(a1h[1], t1[1], d1h[1]);
    base2[3][0] = fmaf(a1h[2], t1[2], d1h[2]); base2[3][1] = fmaf(a1h[3], t1[3], d1h[3]);
#pragma unroll
    for (int ih = 0; ih < 2; ++ih) {
        float axs = A_[2 * w + ih];
        f32x2 ax2 = {axs, axs};
        f32x2 tc2[4];
#pragma unroll
        for (int e = 0; e < 4; ++e) tc2[e] = __builtin_elementwise_fma(wgx2[e], ax2, base2[e]);
#pragma unroll
        for (int kk = 0; kk < 4; ++kk) {
            int iy = nh + 2 * kk;
            float ays = A_[iy];
            f32x2 ay2 = {ays, ays};
            f32x2 z = {0.f, 0.f};
            int n = w * 16 + ih * 8 + iy;
            bf16x8 out;
            bf16x2* o2 = (bf16x2*)&out;
#pragma unroll
            for (int e = 0; e < 4; ++e) {
                f32x2 v = __builtin_elementwise_max(
                    __builtin_elementwise_fma(wgy2[e], ay2, tc2[e]), z);
                o2[e] = cvt2(v[0], v[1]);
            }
            *(bf16x8*)(&y1[n * 264 + c0]) = out;
        }
    }
}

// ---------------- K1a: tokpart = tokens @ W1[:C] ; per-channel stats ; coarse -------
__global__ __launch_bounds__(256) void k1a(const float* __restrict__ tokens,
                                           const __bf16* __restrict__ W1p,
                                           const float* __restrict__ Wc,
                                           const float* __restrict__ bc,
                                           float* __restrict__ tokpart,
                                           float* __restrict__ coarse,
                                           float* __restrict__ p1s,
                                           float* __restrict__ p1q) {
    __shared__ __align__(16) __bf16 Al[16 * 264];
    int t = threadIdx.x, w = t >> 6, l = t & 63;
    int quad = l >> 4, col = l & 15;
    int rowbase = (blockIdx.x >> 1) * 16;
    int colhalf = blockIdx.x & 1;
    int slot = blockIdx.x & 31;

    bf16x8 bfr[16];
#pragma unroll
    for (int ctl = 0; ctl < 2; ++ctl)
#pragma unroll
        for (int ks = 0; ks < 8; ++ks) {
            int CT = colhalf * 8 + w * 2 + ctl;
            bfr[ctl * 8 + ks] = *(const bf16x8*)(W1p + (((CT * 8 + ks) * 64 + l) * 8));
        }
    {
        int r = t >> 4, cb = (t & 15) * 16;
        const float* src = tokens + (size_t)(rowbase + r) * C_ + cb;
        f32x4 t0 = *(const f32x4*)(src);
        f32x4 t1 = *(const f32x4*)(src + 4);
        f32x4 t2 = *(const f32x4*)(src + 8);
        f32x4 t3 = *(const f32x4*)(src + 12);
        bf16x8 v0, v1;
        bf16x2* p0 = (bf16x2*)&v0; bf16x2* p1 = (bf16x2*)&v1;
        p0[0] = cvt2(t0[0], t0[1]); p0[1] = cvt2(t0[2], t0[3]);
        p0[2] = cvt2(t1[0], t1[1]); p0[3] = cvt2(t1[2], t1[3]);
        p1[0] = cvt2(t2[0], t2[1]); p1[1] = cvt2(t2[2], t2[3]);
        p1[2] = cvt2(t3[0], t3[1]); p1[3] = cvt2(t3[2], t3[3]);
        *(bf16x8*)(&Al[r * 264 + cb]) = v0;
        *(bf16x8*)(&Al[r * 264 + cb + 8]) = v1;
    }
    __syncthreads();

    bf16x8 af[8];
#pragma unroll
    for (int ks = 0; ks < 8; ++ks)
        af[ks] = *(const bf16x8*)(&Al[col * 264 + ks * 32 + quad * 8]);

#pragma unroll
    for (int ctl = 0; ctl < 2; ++ctl) {
        f32x4 acc = {0.f, 0.f, 0.f, 0.f};
#pragma unroll
        for (int ks = 0; ks < 8; ++ks)
            acc = __builtin_amdgcn_mfma_f32_16x16x32_bf16(af[ks], bfr[ctl * 8 + ks], acc, 0, 0, 0);
        int c = colhalf * 128 + w * 32 + ctl * 16 + col;
        float s = 0.f, q = 0.f;
#pragma unroll
        for (int rr = 0; rr < 4; ++rr) {
            float v = acc[rr];
            tokpart[(size_t)(rowbase + quad * 4 + rr) * C_ + c] = v;
            s += v; q += v * v;
        }
        s += __shfl_xor(s, 16, 64); s += __shfl_xor(s, 32, 64);
        q += __shfl_xor(q, 16, 64); q += __shfl_xor(q, 32, 64);
        if (l < 16) {
            int cc = colhalf * 128 + w * 32 + ctl * 16 + l;
            atomicAdd(p1s + slot * C_ + cc, s);
            atomicAdd(p1q + slot * C_ + cc, q);
        }
    }
    // coarse (only one colhalf does it): wave w -> rows w*4..w*4+3, lane l -> ch l*4..+4
    if (colhalf == 0) {
        const f32x4* wcp = (const f32x4*)(Wc + l * 12);
        f32x4 wa = wcp[0], wb = wcp[1], wv = wcp[2];
        float wcl[12] = {wa[0], wa[1], wa[2], wa[3], wb[0], wb[1], wb[2], wb[3],
                         wv[0], wv[1], wv[2], wv[3]};
#pragma unroll
        for (int rr = 0; rr < 4; ++rr) {
            int r = w * 4 + rr;
            bf16x4 tv4 = *(const bf16x4*)(&Al[r * 264 + l * 4]);
            float p[3] = {0.f, 0.f, 0.f};
#pragma unroll
            for (int i = 0; i < 4; ++i) {
                float tvf = (float)tv4[i];
#pragma unroll
                for (int j = 0; j < 3; ++j) p[j] = fmaf(tvf, wcl[i * 3 + j], p[j]);
            }
#pragma unroll
            for (int off = 1; off < 64; off <<= 1)
#pragma unroll
                for (int j = 0; j < 3; ++j) p[j] += __shfl_xor(p[j], off, 64);
            if (l == 0) {
#pragma unroll
                for (int j = 0; j < 3; ++j)
                    coarse[(size_t)(rowbase + r) * 3 + j] = p[j] + bc[j];
            }
        }
    }
}

// ---------------- K1b: BN1 params ---------------------------------------------------
__global__ void k1b(const float* __restrict__ grid, const float* __restrict__ W1,
                    const float* __restrict__ gamma1, const float* __restrict__ beta1,
                    const float* __restrict__ p1s, const float* __restrict__ p1q,
                    float* __restrict__ a1o, float* __restrict__ d1o) {
    int t = threadIdx.x;
    float S = 0.f, Qq = 0.f;
    for (int s = 0; s < 32; ++s) { S += p1s[s * C_ + t]; Qq += p1q[s * C_ + t]; }
    float mean_t = S / (float)ROWS;
    float var_t = Qq / (float)ROWS - mean_t * mean_t;
    float wx = W1[C_ * H1_ + t];
    float wy = W1[(C_ + 1) * H1_ + t];
    float mg = 0.f, qg = 0.f;
    for (int n = 0; n < 64; ++n) {
        float gv = grid[2 * n] * wx + grid[2 * n + 1] * wy;
        mg += gv; qg += gv * gv;
    }
    mg *= (1.f / 64.f);
    float var_g = qg * (1.f / 64.f) - mg * mg;
    float a1 = gamma1[t] * rsqrtf(var_t + var_g + EPSN);
    a1o[t] = a1;
    d1o[t] = beta1[t] - a1 * (mean_t + mg);
}

// ---------------- K2: y1 once, GEMM once, stats (+optionally spill h2pre bf16) ------
template <bool SPILL>
__global__ __launch_bounds__(256) void k2(const float* __restrict__ tokpart,
                                          const float* __restrict__ grid,
                                          const float* __restrict__ W1,
                                          const __bf16* __restrict__ W2p,
                                          const float* __restrict__ a1,
                                          const float* __restrict__ d1,
                                          float* __restrict__ p2s,
                                          float* __restrict__ p2q,
                                          __bf16* __restrict__ h2s) {
    __shared__ __align__(16) __bf16 y1[64 * 264];
    __shared__ __align__(16) __bf16 y2l[SPILL ? 64 * 72 : 8];
    int t = threadIdx.x, w = t >> 6, l = t & 63;
    int quad = l >> 4, col = l & 15;
    int wn = w >> 1, wc = w & 1;
    int c0 = (l & 31) * 8, nh = l >> 5;

    bf16x8 bfr[16];
#pragma unroll
    for (int ck = 0; ck < 2; ++ck)
#pragma unroll
        for (int ks = 0; ks < 8; ++ks)
            bfr[ck * 8 + ks] = *(const bf16x8*)(W2p + ((((wc * 2 + ck) * 8 + ks) * 64 + l) * 8));

    f32x2 wgx2[4], wgy2[4]; float A_[8];
    prep_ctx(grid, W1, a1, c0, wgx2, wgy2, A_);

    float s[2][4] = {}, q[2][4] = {};

#pragma unroll 1
    for (int r8 = 0; r8 < 8; ++r8) {
        int row = blockIdx.x * 8 + r8;
        stage16(y1, w, c0, nh, a1, d1, wgx2, wgy2, A_, tokpart + (size_t)row * C_);
        __syncthreads();
#pragma unroll
        for (int rt = 0; rt < 2; ++rt) {
            bf16x8 af[8];
#pragma unroll
            for (int ks = 0; ks < 8; ++ks)
                af[ks] = *(const bf16x8*)(&y1[(wn * 32 + rt * 16 + col) * 264 + ks * 32 + quad * 8]);
#pragma unroll
            for (int ck = 0; ck < 2; ++ck) {
                f32x4 acc = {0.f, 0.f, 0.f, 0.f};
#pragma unroll
                for (int ks = 0; ks < 8; ++ks)
                    acc = __builtin_amdgcn_mfma_f32_16x16x32_bf16(bfr[ck * 8 + ks], af[ks], acc, 0, 0, 0);
                // acc[rr] = h2pre[n = wn*32+rt*16+col][c2 = wc*32+ck*16+quad*4+rr] (raw, no b2)
#pragma unroll
                for (int rr = 0; rr < 4; ++rr) {
                    s[ck][rr] += acc[rr];
                    q[ck][rr] += acc[rr] * acc[rr];
                }
                if constexpr (SPILL) {
                    bf16x4 v; bf16x2* v2 = (bf16x2*)&v;
                    v2[0] = cvt2(acc[0], acc[1]);
                    v2[1] = cvt2(acc[2], acc[3]);
                    *(bf16x4*)(&y2l[(wn * 32 + rt * 16 + col) * 72 + wc * 32 + ck * 16 + quad * 4]) = v;
                }
            }
        }
        __syncthreads();
        if constexpr (SPILL) {
            int n = t >> 2, cb = (t & 3) * 16;
            bf16x8 u0 = *(const bf16x8*)(&y2l[n * 72 + cb]);
            bf16x8 u1 = *(const bf16x8*)(&y2l[n * 72 + cb + 8]);
            __bf16* dst = h2s + (size_t)row * 4096 + t * 16;
            *(bf16x8*)dst = u0;
            *(bf16x8*)(dst + 8) = u1;
        }
    }
    int slot = blockIdx.x & 63;
#pragma unroll
    for (int ck = 0; ck < 2; ++ck)
#pragma unroll
        for (int rr = 0; rr < 4; ++rr) {
            float sv = s[ck][rr], qv = q[ck][rr];
            sv += __shfl_xor(sv, 1, 64); sv += __shfl_xor(sv, 2, 64);
            sv += __shfl_xor(sv, 4, 64); sv += __shfl_xor(sv, 8, 64);
            qv += __shfl_xor(qv, 1, 64); qv += __shfl_xor(qv, 2, 64);
            qv += __shfl_xor(qv, 4, 64); qv += __shfl_xor(qv, 8, 64);
            if (col == 0) {
                int c2 = wc * 32 + ck * 16 + quad * 4 + rr;
                atomicAdd(p2s + slot * H2_ + c2, sv);
                atomicAdd(p2q + slot * H2_ + c2, qv);
            }
        }
}

// ---------------- K2b: BN2 params (raw-acc stats; b2 cancels) -----------------------
__global__ void k2b(const float* __restrict__ p2s, const float* __restrict__ p2q,
                    const float* __restrict__ gamma2, const float* __restrict__ beta2,
                    float* __restrict__ a2o, float* __restrict__ d2o) {
    int t = threadIdx.x;
    float S = 0.f, Qq = 0.f;
    for (int s = 0; s < 64; ++s) { S += p2s[s * H2_ + t]; Qq += p2q[s * H2_ + t]; }
    const float invN = 1.f / ((float)ROWS * 64.f);
    float mean = S * invN;
    float var = Qq * invN - mean * mean;
    float a2 = gamma2[t] * rsqrtf(var + EPSN);
    a2o[t] = a2;
    d2o[t] = beta2[t] - a2 * mean;
}

// ---------------- K3 (spill path): read h2s -> BN2+ReLU -> @W3 -> fine --------------
__global__ __launch_bounds__(256) void k3s(const __bf16* __restrict__ h2s,
                                           const float* __restrict__ a2,
                                           const float* __restrict__ d2p,
                                           const __bf16* __restrict__ W3p,
                                           const float* __restrict__ b3,
                                           const float* __restrict__ coarse,
                                           float* __restrict__ fine) {
    __shared__ __align__(16) __bf16 y2l[8][64 * 72];    // 73728 B
    __shared__ __align__(16) float finebuf[8 * 192];    //  6144 B
    int t = threadIdx.x, w = t >> 6, l = t & 63;
    int quad = l >> 4, col = l & 15;

    bf16x8 wfr[2];
#pragma unroll
    for (int ks = 0; ks < 2; ++ks)
        wfr[ks] = *(const bf16x8*)(W3p + ((ks * 64 + l) * 8));

    int n = t >> 2, cb = (t & 3) * 16;
    float a2r[16], d2r[16];
#pragma unroll
    for (int i = 0; i < 16; i += 4) {
        f32x4 av = *(const f32x4*)(a2 + cb + i);
        f32x4 dv = *(const f32x4*)(d2p + cb + i);
#pragma unroll
        for (int e = 0; e < 4; ++e) { a2r[i + e] = av[e]; d2r[i + e] = dv[e]; }
    }
#pragma unroll 1
    for (int r8 = 0; r8 < 8; ++r8) {
        size_t row = (size_t)blockIdx.x * 8 + r8;
        const __bf16* src = h2s + row * 4096 + t * 16;
        bf16x8 u0 = *(const bf16x8*)src;
        bf16x8 u1 = *(const bf16x8*)(src + 8);
        bf16x8 o0, o1;
        bf16x2* p0 = (bf16x2*)&o0; bf16x2* p1 = (bf16x2*)&o1;
#pragma unroll
        for (int e = 0; e < 4; ++e) {
            p0[e] = cvt2(fmaxf(fmaf(a2r[2 * e],     (float)u0[2 * e],     d2r[2 * e]), 0.f),
                         fmaxf(fmaf(a2r[2 * e + 1], (float)u0[2 * e + 1], d2r[2 * e + 1]), 0.f));
            p1[e] = cvt2(fmaxf(fmaf(a2r[8 + 2 * e],     (float)u1[2 * e],     d2r[8 + 2 * e]), 0.f),
                         fmaxf(fmaf(a2r[8 + 2 * e + 1], (float)u1[2 * e + 1], d2r[8 + 2 * e + 1]), 0.f));
        }
        *(bf16x8*)(&y2l[r8][n * 72 + cb]) = o0;
        *(bf16x8*)(&y2l[r8][n * 72 + cb + 8]) = o1;
    }
    __syncthreads();
    float b3v = (col < 3) ? b3[col] : 0.f;
#pragma unroll 1
    for (int r8 = 0; r8 < 8; ++r8) {
        int row = blockIdx.x * 8 + r8;
        bf16x8 af2[2];
#pragma unroll
        for (int ks = 0; ks < 2; ++ks)
            af2[ks] = *(const bf16x8*)(&y2l[r8][(w * 16 + col) * 72 + ks * 32 + quad * 8]);
        f32x4 acc = {0.f, 0.f, 0.f, 0.f};
        acc = __builtin_amdgcn_mfma_f32_16x16x32_bf16(af2[0], wfr[0], acc, 0, 0, 0);
        acc = __builtin_amdgcn_mfma_f32_16x16x32_bf16(af2[1], wfr[1], acc, 0, 0, 0);
        if (col < 3) {
            float cj = coarse[row * 3 + col] + b3v;
#pragma unroll
            for (int rr = 0; rr < 4; ++rr)
                finebuf[r8 * 192 + (w * 16 + quad * 4 + rr) * 3 + col] = acc[rr] + cj;
        }
    }
    __syncthreads();
    {
        float* dst = fine + (size_t)blockIdx.x * 1536;
        const f32x4* fb = (const f32x4*)finebuf;
        *(f32x4*)(dst + 4 * t) = fb[t];
        if (t < 128) *(f32x4*)(dst + 1024 + 4 * t) = fb[256 + t];
    }
}

// ---------------- K3 (fallback): recompute y1, BN2+ReLU, @W3 ------------------------
__global__ __launch_bounds__(256) void k3r(const float* __restrict__ tokpart,
                                           const float* __restrict__ grid,
                                           const float* __restrict__ W1,
                                           const __bf16* __restrict__ W2p,
                                           const float* __restrict__ a1,
                                           const float* __restrict__ d1,
                                           const __bf16* __restrict__ W3p,
                                           const float* __restrict__ a2,
                                           const float* __restrict__ d2p,
                                           const float* __restrict__ b3,
                                           const float* __restrict__ coarse,
                                           float* __restrict__ fine) {
    __shared__ __align__(16) __bf16 y1[64 * 264];
    __shared__ __align__(16) __bf16 y2l[64 * 72];
    __shared__ __align__(16) float finebuf[8 * 192];
    int t = threadIdx.x, w = t >> 6, l = t & 63;
    int quad = l >> 4, col = l & 15;
    int wn = w >> 1, wc = w & 1;
    int c0 = (l & 31) * 8, nh = l >> 5;

    bf16x8 bfr[16];
#pragma unroll
    for (int ck = 0; ck < 2; ++ck)
#pragma unroll
        for (int ks = 0; ks < 8; ++ks)
            bfr[ck * 8 + ks] = *(const bf16x8*)(W2p + ((((wc * 2 + ck) * 8 + ks) * 64 + l) * 8));
    bf16x8 wfr[2];
#pragma unroll
    for (int ks = 0; ks < 2; ++ks)
        wfr[ks] = *(const bf16x8*)(W3p + ((ks * 64 + l) * 8));

    f32x2 wgx2[4], wgy2[4]; float A_[8];
    prep_ctx(grid, W1, a1, c0, wgx2, wgy2, A_);

    float a2v[8], d2v[8];
#pragma unroll
    for (int ck = 0; ck < 2; ++ck)
#pragma unroll
        for (int rr = 0; rr < 4; ++rr) {
            int c2 = wc * 32 + ck * 16 + quad * 4 + rr;
            a2v[ck * 4 + rr] = a2[c2];
            d2v[ck * 4 + rr] = d2p[c2];
        }
    float b3v = (col < 3) ? b3[col] : 0.f;

#pragma unroll 1
    for (int r8 = 0; r8 < 8; ++r8) {
        int row = blockIdx.x * 8 + r8;
        stage16(y1, w, c0, nh, a1, d1, wgx2, wgy2, A_, tokpart + (size_t)row * C_);
        __syncthreads();
#pragma unroll
        for (int rt = 0; rt < 2; ++rt) {
            bf16x8 af[8];
#pragma unroll
            for (int ks = 0; ks < 8; ++ks)
                af[ks] = *(const bf16x8*)(&y1[(wn * 32 + rt * 16 + col) * 264 + ks * 32 + quad * 8]);
#pragma unroll
            for (int ck = 0; ck < 2; ++ck) {
                f32x4 acc = {0.f, 0.f, 0.f, 0.f};
#pragma unroll
                for (int ks = 0; ks < 8; ++ks)
                    acc = __builtin_amdgcn_mfma_f32_16x16x32_bf16(bfr[ck * 8 + ks], af[ks], acc, 0, 0, 0);
                bf16x4 v; bf16x2* v2 = (bf16x2*)&v;
                float y0 = fmaxf(fmaf(a2v[ck * 4 + 0], acc[0], d2v[ck * 4 + 0]), 0.f);
                float y1v = fmaxf(fmaf(a2v[ck * 4 + 1], acc[1], d2v[ck * 4 + 1]), 0.f);
                float y2 = fmaxf(fmaf(a2v[ck * 4 + 2], acc[2], d2v[ck * 4 + 2]), 0.f);
                float y3 = fmaxf(fmaf(a2v[ck * 4 + 3], acc[3], d2v[ck * 4 + 3]), 0.f);
                v2[0] = cvt2(y0, y1v); v2[1] = cvt2(y2, y3);
                *(bf16x4*)(&y2l[(wn * 32 + rt * 16 + col) * 72 + wc * 32 + ck * 16 + quad * 4]) = v;
            }
        }
        __syncthreads();
        bf16x8 af2[2];
#pragma unroll
        for (int ks = 0; ks < 2; ++ks)
            af2[ks] = *(const bf16x8*)(&y2l[(w * 16 + col) * 72 + ks * 32 + quad * 8]);
        f32x4 d2acc = {0.f, 0.f, 0.f, 0.f};
        d2acc = __builtin_amdgcn_mfma_f32_16x16x32_bf16(af2[0], wfr[0], d2acc, 0, 0, 0);
        d2acc = __builtin_amdgcn_mfma_f32_16x16x32_bf16(af2[1], wfr[1], d2acc, 0, 0, 0);
        if (col < 3) {
            float cj = coarse[row * 3 + col] + b3v;
#pragma unroll
            for (int rr = 0; rr < 4; ++rr)
                finebuf[r8 * 192 + (w * 16 + quad * 4 + rr) * 3 + col] = d2acc[rr] + cj;
        }
    }
    __syncthreads();
    {
        float* dst = fine + (size_t)blockIdx.x * 1536;
        const f32x4* fb = (const f32x4*)finebuf;
        *(f32x4*)(dst + 4 * t) = fb[t];
        if (t < 128) *(f32x4*)(dst + 1024 + 4 * t) = fb[256 + t];
    }
}

// ---------------- host launcher -----------------------------------------------------
extern "C" void kernel_launch(void* const* d_in, const int* in_sizes, int n_in,
                              void* d_out, int out_size, void* d_ws, size_t ws_size,
                              hipStream_t stream) {
    (void)in_sizes; (void)n_in; (void)out_size;
    const float* tokens = (const float*)d_in[0];
    const float* grid   = (const float*)d_in[1];
    const float* Wc     = (const float*)d_in[2];
    const float* bc     = (const float*)d_in[3];
    const float* W1     = (const float*)d_in[4];
    const float* gamma1 = (const float*)d_in[6];
    const float* beta1  = (const float*)d_in[7];
    const float* W2     = (const float*)d_in[8];
    const float* gamma2 = (const float*)d_in[10];
    const float* beta2  = (const float*)d_in[11];
    const float* W3     = (const float*)d_in[12];
    const float* b3     = (const float*)d_in[13];

    char* ws = (char*)d_ws;
    __bf16* W1p     = (__bf16*)(ws);                     // 131072 B
    __bf16* W2p     = (__bf16*)(ws + 131072);            //  32768 B
    float*  p1s     = (float*)(ws + 163840);             //  32768 B
    float*  p1q     = (float*)(ws + 196608);             //  32768 B
    float*  p2s     = (float*)(ws + 229376);             //  16384 B
    float*  p2q     = (float*)(ws + 245760);             //  16384 B
    float*  a1      = (float*)(ws + 262144);             //   1024 B
    float*  d1      = (float*)(ws + 263168);             //   1024 B
    float*  a2      = (float*)(ws + 264192);             //    256 B
    float*  d2p     = (float*)(ws + 264448);             //    256 B
    __bf16* W3p     = (__bf16*)(ws + 264704);            //   2048 B
    float*  tokpart = (float*)(ws + 266752);             // 16777216 B
    __bf16* h2s     = (__bf16*)(ws + 17043968);          // 134217728 B (if it fits)

    const size_t SPILL_NEED = 17043968ull + 134217728ull;  // 151261696
    bool spill = ws_size >= SPILL_NEED;

    float* coarse = (float*)d_out;
    float* fine   = (float*)d_out + (size_t)ROWS * 3;

    k0_pack<<<320, 256, 0, stream>>>(W1, W2, W3, W1p, W2p, W3p, p1s);
    k1a<<<2048, 256, 0, stream>>>(tokens, W1p, Wc, bc, tokpart, coarse, p1s, p1q);
    k1b<<<1, 256, 0, stream>>>(grid, W1, gamma1, beta1, p1s, p1q, a1, d1);
    if (spill) {
        k2<true><<<ROWS / 8, 256, 0, stream>>>(tokpart, grid, W1, W2p, a1, d1, p2s, p2q, h2s);
        k2b<<<1, 64, 0, stream>>>(p2s, p2q, gamma2, beta2, a2, d2p);
        k3s<<<ROWS / 8, 256, 0, stream>>>(h2s, a2, d2p, W3p, b3, coarse, fine);
    } else {
        k2<false><<<ROWS / 8, 256, 0, stream>>>(tokpart, grid, W1, W2p, a1, d1, p2s, p2q, h2s);
        k2b<<<1, 64, 0, stream>>>(p2s, p2q, gamma2, beta2, a2, d2p);
        k3r<<<ROWS / 8, 256, 0, stream>>>(tokpart, grid, W1, W2p, a1, d1, W3p, a2, d2p, b3, coarse, fine);
    }
}